// Round 1
// baseline (309.251 us; speedup 1.0000x reference)
//
#include <hip/hip_runtime.h>
#include <stdint.h>

// KANLinear fused kernel for MI355X (gfx950).
// out = x @ bw + scaling * einsum('bik,iok->bo', basis(x), sw)
// Strategy: one bf16 MFMA GEMM, K = 256 i-slabs x 80 (66 basis + base term at k=66 + zero pad).
//   - basis computed on the fly (16-tap window; rest is < 1e-11 and dropped)
//   - W pre-packed to bf16 [i][o][80], pre-scaled by scaling[o], base_weight at k=66 (in d_ws)
//   - BM=64, BN=256, split-K=4 -> 256 blocks (1/CU); partials atomicAdd'ed into zeroed d_out
//   - per-iter pipeline: MFMA(cur) | basis(next)->A[dbuf] | barrier | ds_write staged W regs,
//     issue loads 2 ahead | zero A[cur] | barrier  (loads get a full iter of latency hiding)

#define IN_F 256
#define OUT_F 256
#define NB 66
#define KP 80        // padded K per i-slab (66 basis + 1 base + 13 zeros), = 5 x K16
#define APAD 88      // A LDS row stride in ushorts (176B: balanced banks for b128 col reads)
#define KSPLIT 4
#define ISTEPS (IN_F / KSPLIT)
#define BM 64

typedef __attribute__((ext_vector_type(8))) short bf16x8;
typedef __attribute__((ext_vector_type(16))) float f32x16;

__device__ __forceinline__ unsigned short f2bf(float f) {
  unsigned int u = __float_as_uint(f);
  u += 0x7FFFu + ((u >> 16) & 1u);   // round-to-nearest-even
  return (unsigned short)(u >> 16);
}

// ---- basis window: 16 taps around the active center, normalized, -> bf16 into A row ----
// thread mapping: b = t>>2 (row), q = t&3 (4 taps each). Quad lanes share one b.
__device__ __forceinline__ void basis_window(unsigned short* Ab, const float* __restrict__ x,
                                             int b0, int i, int t) {
  const int b = t >> 2, q = t & 3;
  const float xraw = x[(size_t)(b0 + b) * IN_F + i];
  const float xc = fminf(fmaxf(xraw, -1.0f), 1.0f);
  const float xs = (xc + 1.0f) * (63.0f / (2.0f + 1e-7f));   // x_norm * (GRID_SIZE-1)
  const float tl = xs - fminf(floorf(xs), 61.0f);            // local_x in [0,2)
  int kc = (int)(tl * 65.0f + 0.5f);                         // nearest center index
  const int k0 = max(0, min(kc - 8, 50));                    // 16-tap window start
  const int kq = k0 + q * 4;
  const float inv65 = 1.0f / 65.0f;
  float d0 = tl - (float)(kq + 0) * inv65;
  float d1 = tl - (float)(kq + 1) * inv65;
  float d2 = tl - (float)(kq + 2) * inv65;
  float d3 = tl - (float)(kq + 3) * inv65;
  // exp(-d^2/(2*sigma^2)), sigma=1/66 -> coef 2178
  float e0 = __expf(-2178.0f * d0 * d0);
  float e1 = __expf(-2178.0f * d1 * d1);
  float e2 = __expf(-2178.0f * d2 * d2);
  float e3 = __expf(-2178.0f * d3 * d3);
  float s = e0 + e1 + e2 + e3;
  s += __shfl_xor(s, 1);
  s += __shfl_xor(s, 2);
  const float r = __fdividef(1.0f, s + 1e-7f);
  unsigned short* Ar = Ab + (size_t)b * APAD;
  Ar[kq + 0] = f2bf(e0 * r);
  Ar[kq + 1] = f2bf(e1 * r);
  Ar[kq + 2] = f2bf(e2 * r);
  Ar[kq + 3] = f2bf(e3 * r);
  if (q == 0) Ar[66] = f2bf(xraw);   // base-GEMM term (raw x, not clipped)
}

// zero one wave's 16 rows of an A buffer (16*88 ushorts = 704 uints; 11 per lane)
__device__ __forceinline__ void zero_wave_rows(unsigned short* Ab, int w, int lane) {
  unsigned int* Az = (unsigned int*)(Ab + (size_t)w * 16 * APAD);
  #pragma unroll
  for (int j = 0; j < 11; j++) Az[j * 64 + lane] = 0u;
}

// ---- scaling[o] = mean_i max(scaler[i,o], eps); 64 blocks x 4 i's, atomic into ws ----
__global__ void kan_scale(const float* __restrict__ scaler, float* __restrict__ wsc) {
  const int o = threadIdx.x;
  float s = 0.0f;
  #pragma unroll
  for (int ii = 0; ii < 4; ii++) {
    int i = blockIdx.x * 4 + ii;
    s += fmaxf(scaler[(size_t)i * OUT_F + o], 1e-7f);
  }
  atomicAdd(&wsc[o], s * (1.0f / 256.0f));
}

// ---- pack W' [i][o][80] bf16: k<66 = sw*scaling[o]; k=66 = bw; rest 0 ----
__global__ void kan_pack(const float* __restrict__ sw, const float* __restrict__ bw,
                         const float* __restrict__ wsc, unsigned short* __restrict__ wp) {
  const int i = blockIdx.x, o = threadIdx.x;
  const float sc = wsc[o];
  const float2* src = (const float2*)(sw + ((size_t)i * OUT_F + o) * NB);   // 66 = 33 float2, 8B aligned
  ushort2* dst = (ushort2*)(wp + ((size_t)i * OUT_F + o) * KP);
  #pragma unroll
  for (int j = 0; j < 33; j++) {
    float2 v = src[j];
    ushort2 p; p.x = f2bf(v.x * sc); p.y = f2bf(v.y * sc);
    dst[j] = p;
  }
  ushort2 pb; pb.x = f2bf(bw[(size_t)i * OUT_F + o]); pb.y = 0;
  dst[33] = pb;
  ushort2 z; z.x = 0; z.y = 0;
  #pragma unroll
  for (int j = 34; j < 40; j++) dst[j] = z;
}

// ---- main fused GEMM ----
__global__ __launch_bounds__(256, 1) void kan_main(const float* __restrict__ x,
                                                   const unsigned short* __restrict__ wp,
                                                   float* __restrict__ out) {
  __shared__ unsigned short A[2][BM * APAD];   // 22528 B (double-buffered basis tile)
  __shared__ unsigned short Bt[OUT_F * KP];    // 40960 B (single-buffered W' slab)
  // total 63.5 KB static LDS

  const int t = threadIdx.x;
  const int lane = t & 63;
  const int w = t >> 6;
  const int b0 = blockIdx.x * BM;
  const int i0 = blockIdx.y * ISTEPS;

  uint4 rg[10];   // staged W' row (80 ushorts = 160B) for slab ii+1

  // ---- prologue ----
  {
    unsigned int* Az = (unsigned int*)&A[0][0];   // zero both A buffers (5632 uints)
    #pragma unroll
    for (int j = 0; j < 22; j++) Az[j * 256 + t] = 0u;
    __threadfence_block();   // order zero (uint) vs window writes (ushort) within wave
    const uint4* g0 = (const uint4*)(wp + ((size_t)i0 * OUT_F + t) * KP);
    #pragma unroll
    for (int j = 0; j < 10; j++) rg[j] = g0[j];
    basis_window(&A[0][0], x, b0, i0, t);
    uint4* d0 = (uint4*)(Bt + (size_t)t * KP);
    #pragma unroll
    for (int j = 0; j < 10; j++) d0[j] = rg[j];
    const uint4* g1 = (const uint4*)(wp + ((size_t)(i0 + 1) * OUT_F + t) * KP);
    #pragma unroll
    for (int j = 0; j < 10; j++) rg[j] = g1[j];
  }
  __syncthreads();

  f32x16 acc00 = {}, acc01 = {}, acc10 = {}, acc11 = {};
  const int ml = lane & 31;
  const int half = lane >> 5;

  for (int ii = 0; ii < ISTEPS; ii++) {
    const int cur = ii & 1;
    // (a) MFMA over slab ii: wave tile 64x64 = 2x2 of 32x32, K=80 = 5 x K16
    const unsigned short* Ac = &A[cur][0];
    #pragma unroll
    for (int kk = 0; kk < 5; kk++) {
      const int ko = kk * 16 + half * 8;
      bf16x8 a0  = *(const bf16x8*)(Ac + ml * APAD + ko);
      bf16x8 a1  = *(const bf16x8*)(Ac + (32 + ml) * APAD + ko);
      bf16x8 bb0 = *(const bf16x8*)(Bt + (w * 64 + ml) * KP + ko);
      bf16x8 bb1 = *(const bf16x8*)(Bt + (w * 64 + 32 + ml) * KP + ko);
      acc00 = __builtin_amdgcn_mfma_f32_32x32x16_bf16(a0, bb0, acc00, 0, 0, 0);
      acc01 = __builtin_amdgcn_mfma_f32_32x32x16_bf16(a0, bb1, acc01, 0, 0, 0);
      acc10 = __builtin_amdgcn_mfma_f32_32x32x16_bf16(a1, bb0, acc10, 0, 0, 0);
      acc11 = __builtin_amdgcn_mfma_f32_32x32x16_bf16(a1, bb1, acc11, 0, 0, 0);
    }
    // (b) basis for slab ii+1 into the other A buffer (zeroed last iter); overlaps MFMA
    if (ii + 1 < ISTEPS) basis_window(&A[1 - cur][0], x, b0, i0 + ii + 1, t);
    __syncthreads();   // all waves done reading Bt and A[cur]
    // (e) commit staged W' slab ii+1 to Bt; issue loads for slab ii+2 (hidden a full iter)
    if (ii + 1 < ISTEPS) {
      uint4* d = (uint4*)(Bt + (size_t)t * KP);
      #pragma unroll
      for (int j = 0; j < 10; j++) d[j] = rg[j];
      if (ii + 2 < ISTEPS) {
        const uint4* g = (const uint4*)(wp + ((size_t)(i0 + ii + 2) * OUT_F + t) * KP);
        #pragma unroll
        for (int j = 0; j < 10; j++) rg[j] = g[j];
      }
    }
    zero_wave_rows(&A[cur][0], w, lane);   // prep A[cur] for next iter's basis
    __syncthreads();
  }

  // ---- epilogue: C/D layout col=lane&31, row=(r&3)+8*(r>>2)+4*(lane>>5) ----
  const int colb = w * 64 + ml;
  const int rowb = b0 + 4 * half;
  #pragma unroll
  for (int r = 0; r < 16; r++) {
    const int ro = (r & 3) + 8 * (r >> 2);
    atomicAdd(&out[(size_t)(rowb + ro) * OUT_F + colb],            acc00[r]);
    atomicAdd(&out[(size_t)(rowb + ro) * OUT_F + colb + 32],       acc01[r]);
    atomicAdd(&out[(size_t)(rowb + 32 + ro) * OUT_F + colb],       acc10[r]);
    atomicAdd(&out[(size_t)(rowb + 32 + ro) * OUT_F + colb + 32],  acc11[r]);
  }
}

// ---- naive fallback (only if d_ws is too small): correct, slow ----
__global__ void kan_naive(const float* __restrict__ x, const float* __restrict__ bw,
                          const float* __restrict__ sw, const float* __restrict__ sca,
                          float* __restrict__ out) {
  const int o = threadIdx.x;
  const int b = blockIdx.x;
  float accb = 0.0f, accs = 0.0f, scl = 0.0f;
  for (int i = 0; i < IN_F; i++) {
    const float xraw = x[(size_t)b * IN_F + i];
    accb += xraw * bw[(size_t)i * OUT_F + o];
    scl += fmaxf(sca[(size_t)i * OUT_F + o], 1e-7f);
    const float xc = fminf(fmaxf(xraw, -1.0f), 1.0f);
    const float xs = (xc + 1.0f) * (63.0f / (2.0f + 1e-7f));
    const float tl = xs - fminf(floorf(xs), 61.0f);
    const int kc = (int)(tl * 65.0f + 0.5f);
    const int k0 = max(0, min(kc - 8, 50));
    float e[16]; float s = 0.0f;
    #pragma unroll
    for (int j = 0; j < 16; j++) {
      float d = tl - (float)(k0 + j) * (1.0f / 65.0f);
      e[j] = __expf(-2178.0f * d * d);
      s += e[j];
    }
    const float r = __fdividef(1.0f, s + 1e-7f);
    const float* wrow = sw + ((size_t)i * OUT_F + o) * NB + k0;
    float dot = 0.0f;
    #pragma unroll
    for (int j = 0; j < 16; j++) dot += e[j] * wrow[j];
    accs += dot * r;
  }
  out[(size_t)b * OUT_F + o] = accb + accs * (scl * (1.0f / 256.0f));
}

extern "C" void kernel_launch(void* const* d_in, const int* in_sizes, int n_in,
                              void* d_out, int out_size, void* d_ws, size_t ws_size,
                              hipStream_t stream) {
  const float* x   = (const float*)d_in[0];
  const float* bw  = (const float*)d_in[1];
  const float* sw  = (const float*)d_in[2];
  const float* sca = (const float*)d_in[3];
  float* out = (float*)d_out;
  const size_t WP_BYTES = (size_t)IN_F * OUT_F * KP * sizeof(unsigned short);  // 10.49 MB
  const size_t NEED = 1024 + WP_BYTES;
  if (ws_size >= NEED) {
    float* wsc = (float*)d_ws;
    unsigned short* wp = (unsigned short*)((char*)d_ws + 1024);
    hipMemsetAsync(d_ws, 0, 1024, stream);                       // scaling accumulators
    hipMemsetAsync(d_out, 0, (size_t)out_size * sizeof(float), stream);
    kan_scale<<<64, 256, 0, stream>>>(sca, wsc);
    kan_pack<<<256, 256, 0, stream>>>(sw, bw, wsc, wp);
    kan_main<<<dim3(64, KSPLIT), 256, 0, stream>>>(x, wp, out);
  } else {
    kan_naive<<<4096, 256, 0, stream>>>(x, bw, sw, sca, out);
  }
}

// Round 2
// 154.945 us; speedup vs baseline: 1.9959x; 1.9959x over previous
//
#include <hip/hip_runtime.h>
#include <stdint.h>

// KANLinear fused kernel v2 for MI355X (gfx950).
// out = x @ bw + scaling * einsum('bik,iok->bo', basis(x), sw)
// One bf16 MFMA GEMM: K = 256 i-slabs x 80 (66 basis + base term at k=66 + zero pad).
// v2 changes vs v1 (which was latency-bound: MfmaUtil 7.3%, Occ 11.6%):
//   - 512-thr blocks, BM=128, wave tile 64x64, splitK=8, grid 256 (kidx = blk&7 for XCD-L2)
//   - B consumed from global (L2-hot wp2, coalesced layout) into double-buffered regs: no
//     Bt LDS staging, ONE barrier per slab instead of two
//   - full-row basis: each quad thread computes+writes a 16B-aligned span of all 80 k's
//     (Gaussian tails are the zeros) -> no zero pass, no scatter, exact reference math
//   - epilogue: per-split partial tiles in d_ws + reduce kernel (no atomics); atomic
//     fallback if ws is small

#define IN_F 256
#define OUT_F 256
#define NB 66
#define KP 80        // padded K per i-slab: 66 basis + base at k=66 + zeros, = 5 x K16
#define APAD 88      // A LDS row stride in ushorts
#define KSPLIT 8
#define SLABS 32     // IN_F / KSPLIT
#define BM 128
#define NTHREADS 512

typedef __attribute__((ext_vector_type(8))) short bf16x8;
typedef __attribute__((ext_vector_type(16))) float f32x16;

__device__ __forceinline__ unsigned int f2bf(float f) {
  unsigned int u = __float_as_uint(f);
  u += 0x7FFFu + ((u >> 16) & 1u);   // round-to-nearest-even
  return u >> 16;
}

// ---- scaling partial: block b sums i in [b*32, b*32+32); pack kernel finishes the mean ----
__global__ void kan_scale8(const float* __restrict__ sca, float* __restrict__ wsp) {
  const int o = threadIdx.x, b = blockIdx.x;
  float s = 0.0f;
  #pragma unroll
  for (int j = 0; j < 32; j++) {
    const int i = b * 32 + j;
    s += fmaxf(sca[(size_t)i * OUT_F + o], 1e-7f);
  }
  wsp[b * OUT_F + o] = s;
}

// ---- pack W' -> wp2, layout (i*10 + g)*256 + o of 8-bf16 chunks, g = kk*2+half ----
// k<66 = sw*scaling[o]; k=66 = bw; 67..79 = 0. Coalesced uint4 stores.
__global__ void kan_pack(const float* __restrict__ sw, const float* __restrict__ bw,
                         const float* __restrict__ wsp, unsigned short* __restrict__ wp2) {
  const int i = blockIdx.x, o = threadIdx.x;
  float sc = 0.0f;
  #pragma unroll
  for (int b = 0; b < 8; b++) sc += wsp[b * OUT_F + o];
  sc *= (1.0f / 256.0f);
  const float2* src = (const float2*)(sw + ((size_t)i * OUT_F + o) * NB);
  float v[80];
  #pragma unroll
  for (int j = 0; j < 33; j++) {
    float2 t2 = src[j];
    v[2 * j] = t2.x * sc;
    v[2 * j + 1] = t2.y * sc;
  }
  v[66] = bw[(size_t)i * OUT_F + o];
  #pragma unroll
  for (int k = 67; k < 80; k++) v[k] = 0.0f;
  uint4* dst = (uint4*)wp2;
  #pragma unroll
  for (int g = 0; g < 10; g++) {
    uint4 u;
    unsigned int* up = (unsigned int*)&u;
    #pragma unroll
    for (int h = 0; h < 4; h++)
      up[h] = f2bf(v[g * 8 + 2 * h]) | (f2bf(v[g * 8 + 2 * h + 1]) << 16);
    dst[((size_t)i * 10 + g) * OUT_F + o] = u;
  }
}

// ---- main fused GEMM ----
__global__ __launch_bounds__(NTHREADS, 2) void kan_main(
    const float* __restrict__ x, const unsigned short* __restrict__ wp2,
    float* __restrict__ dst, int atomic_mode) {
  __shared__ unsigned short A[2][BM * APAD];   // 45056 B

  const int t = threadIdx.x;
  const int lane = t & 63;
  const int w = t >> 6;            // 0..7
  const int ml = lane & 31;
  const int half = lane >> 5;
  const int mr = w >> 2;           // wave M-row: 0..1 (64 rows each)
  const int nc = w & 3;            // wave N-col: 0..3 (64 cols each)
  const int mblk = (int)blockIdx.x >> 3;
  const int kidx = (int)blockIdx.x & 7;   // XCD-affine split-K index
  const int b0 = mblk * BM;
  const int ibase = kidx * SLABS;

  // basis thread mapping: row rb = t>>2, quad thread q covers 16B-aligned span
  const int rb = t >> 2;           // 0..127
  const int q = t & 3;
  const int ks = (q == 0) ? 0 : (q == 1) ? 24 : (q == 2) ? 40 : 64;
  const int len = (q & 1) ? 16 : 24;
  const int nchunk = len >> 3;

  const float* xrow = x + (size_t)(b0 + rb) * IN_F;
  const int boff = (nc * 64 + ml) * 8;   // ushort offset of this lane's B row chunk

  bf16x8 breg[2][10];
  f32x16 acc[4] = {f32x16{}, f32x16{}, f32x16{}, f32x16{}};

#define LOADB(P, ISLAB)                                                        \
  {                                                                            \
    const unsigned short* bp =                                                 \
        wp2 + (size_t)(ISLAB) * (OUT_F * KP) + half * 2048 + boff;             \
    _Pragma("unroll") for (int kk = 0; kk < 5; kk++) {                         \
      breg[P][kk] = *(const bf16x8*)(bp + kk * 4096);                          \
      breg[P][5 + kk] = *(const bf16x8*)(bp + kk * 4096 + 256);                \
    }                                                                          \
  }

#define BASIS(BUFSEL, XVAL)                                                    \
  {                                                                            \
    const float xr_ = (XVAL);                                                  \
    const float xc_ = fminf(fmaxf(xr_, -1.0f), 1.0f);                          \
    const float xs_ = (xc_ + 1.0f) * (63.0f / (2.0f + 1e-7f));                 \
    const float tl_ = xs_ - fminf(floorf(xs_), 61.0f);                         \
    float e_[24];                                                              \
    float s_ = 0.0f;                                                           \
    _Pragma("unroll") for (int j = 0; j < 24; j++) {                           \
      const int k = ks + j;                                                    \
      const float d_ = tl_ - (float)k * (1.0f / 65.0f);                        \
      float ee = __expf(-2178.0f * d_ * d_);                                   \
      ee = (j < len && k < 66) ? ee : 0.0f;                                    \
      e_[j] = ee;                                                              \
      s_ += ee;                                                                \
    }                                                                          \
    s_ += __shfl_xor(s_, 1);                                                   \
    s_ += __shfl_xor(s_, 2);                                                   \
    const float r_ = __fdividef(1.0f, s_ + 1e-7f);                             \
    unsigned short* Ar = &A[BUFSEL][rb * APAD + ks];                           \
    _Pragma("unroll") for (int c = 0; c < 3; c++) {                            \
      if (c < nchunk) {                                                        \
        uint4 u;                                                               \
        unsigned int* up = (unsigned int*)&u;                                  \
        _Pragma("unroll") for (int h = 0; h < 4; h++) {                        \
          const int k0 = ks + c * 8 + h * 2;                                   \
          float f0 = e_[c * 8 + h * 2] * r_;                                   \
          float f1 = e_[c * 8 + h * 2 + 1] * r_;                               \
          f0 = (k0 == 66) ? xr_ : f0;                                          \
          f1 = (k0 + 1 == 66) ? xr_ : f1;                                      \
          up[h] = f2bf(f0) | (f2bf(f1) << 16);                                 \
        }                                                                      \
        *(uint4*)(Ar + c * 8) = u;                                             \
      }                                                                        \
    }                                                                          \
  }

#define MFMA_SLAB(CUR, P)                                                      \
  {                                                                            \
    const unsigned short* Ac = &A[CUR][0];                                     \
    _Pragma("unroll") for (int kk = 0; kk < 5; kk++) {                         \
      const int ko = kk * 16 + half * 8;                                       \
      bf16x8 a0 = *(const bf16x8*)(Ac + (mr * 64 + ml) * APAD + ko);           \
      bf16x8 a1 = *(const bf16x8*)(Ac + (mr * 64 + 32 + ml) * APAD + ko);      \
      acc[0] = __builtin_amdgcn_mfma_f32_32x32x16_bf16(a0, breg[P][kk], acc[0], 0, 0, 0);       \
      acc[1] = __builtin_amdgcn_mfma_f32_32x32x16_bf16(a0, breg[P][5 + kk], acc[1], 0, 0, 0);   \
      acc[2] = __builtin_amdgcn_mfma_f32_32x32x16_bf16(a1, breg[P][kk], acc[2], 0, 0, 0);       \
      acc[3] = __builtin_amdgcn_mfma_f32_32x32x16_bf16(a1, breg[P][5 + kk], acc[3], 0, 0, 0);   \
    }                                                                          \
  }

  // ---- prologue: slab 0 basis + B regs ----
  BASIS(0, xrow[ibase]);
  LOADB(0, ibase);
  float xn = xrow[ibase + 1];
  __syncthreads();

#define STEP(II, P)                                                            \
  {                                                                            \
    if ((II) + 1 < SLABS) LOADB(1 - (P), ibase + (II) + 1);                    \
    MFMA_SLAB((II) & 1, P);                                                    \
    const float xc2 = xn;                                                      \
    if ((II) + 2 < SLABS) xn = xrow[ibase + (II) + 2];                         \
    if ((II) + 1 < SLABS) BASIS(((II) + 1) & 1, xc2);                          \
    __syncthreads();                                                           \
  }

  for (int ii = 0; ii < SLABS; ii += 2) {
    STEP(ii, 0);
    STEP(ii + 1, 1);
  }

  // ---- epilogue: C/D layout col=lane&31, row=(r&3)+8*(r>>2)+4*(lane>>5) ----
  const int colb = nc * 64 + ml;
  if (atomic_mode) {
    #pragma unroll
    for (int mb = 0; mb < 2; mb++) {
      #pragma unroll
      for (int r = 0; r < 16; r++) {
        const int row = b0 + mr * 64 + mb * 32 + (r & 3) + 8 * (r >> 2) + 4 * half;
        atomicAdd(&dst[(size_t)row * OUT_F + colb], acc[mb * 2][r]);
        atomicAdd(&dst[(size_t)row * OUT_F + colb + 32], acc[mb * 2 + 1][r]);
      }
    }
  } else {
    float* pd = dst + (size_t)kidx * ((size_t)4096 * OUT_F);
    #pragma unroll
    for (int mb = 0; mb < 2; mb++) {
      #pragma unroll
      for (int r = 0; r < 16; r++) {
        const int row = b0 + mr * 64 + mb * 32 + (r & 3) + 8 * (r >> 2) + 4 * half;
        pd[(size_t)row * OUT_F + colb] = acc[mb * 2][r];
        pd[(size_t)row * OUT_F + colb + 32] = acc[mb * 2 + 1][r];
      }
    }
  }
}

// ---- split-K reduce: out = sum of 8 partial tiles ----
__global__ void kan_reduce(const float* __restrict__ part, float* __restrict__ out) {
  const size_t j = ((size_t)blockIdx.x * 256 + threadIdx.x) * 4;
  float4 a = *(const float4*)(part + j);
  #pragma unroll
  for (int s = 1; s < 8; s++) {
    float4 b = *(const float4*)(part + (size_t)s * 1048576 + j);
    a.x += b.x; a.y += b.y; a.z += b.z; a.w += b.w;
  }
  *(float4*)(out + j) = a;
}

// ---- naive fallback (only if d_ws is too small): correct, slow ----
__global__ void kan_naive(const float* __restrict__ x, const float* __restrict__ bw,
                          const float* __restrict__ sw, const float* __restrict__ sca,
                          float* __restrict__ out) {
  const int o = threadIdx.x;
  const int b = blockIdx.x;
  float accb = 0.0f, accs = 0.0f, scl = 0.0f;
  for (int i = 0; i < IN_F; i++) {
    const float xraw = x[(size_t)b * IN_F + i];
    accb += xraw * bw[(size_t)i * OUT_F + o];
    scl += fmaxf(sca[(size_t)i * OUT_F + o], 1e-7f);
    const float xc = fminf(fmaxf(xraw, -1.0f), 1.0f);
    const float xs = (xc + 1.0f) * (63.0f / (2.0f + 1e-7f));
    const float tl = xs - fminf(floorf(xs), 61.0f);
    const int kc = (int)(tl * 65.0f + 0.5f);
    const int k0 = max(0, min(kc - 8, 50));
    float e[16]; float s = 0.0f;
    #pragma unroll
    for (int j = 0; j < 16; j++) {
      float d = tl - (float)(k0 + j) * (1.0f / 65.0f);
      e[j] = __expf(-2178.0f * d * d);
      s += e[j];
    }
    const float r = __fdividef(1.0f, s + 1e-7f);
    const float* wrow = sw + ((size_t)i * OUT_F + o) * NB + k0;
    float dot = 0.0f;
    #pragma unroll
    for (int j = 0; j < 16; j++) dot += e[j] * wrow[j];
    accs += dot * r;
  }
  out[(size_t)b * OUT_F + o] = accb + accs * (scl * (1.0f / 256.0f));
}

extern "C" void kernel_launch(void* const* d_in, const int* in_sizes, int n_in,
                              void* d_out, int out_size, void* d_ws, size_t ws_size,
                              hipStream_t stream) {
  const float* x   = (const float*)d_in[0];
  const float* bw  = (const float*)d_in[1];
  const float* sw  = (const float*)d_in[2];
  const float* sca = (const float*)d_in[3];
  float* out = (float*)d_out;

  const size_t WP2_BYTES  = (size_t)IN_F * OUT_F * KP * 2;          // 10485760
  const size_t WP_OFF     = 8192;                                   // after wsp[8][256]
  const size_t PART_OFF   = WP_OFF + WP2_BYTES;                     // 10493952
  const size_t PART_BYTES = (size_t)KSPLIT * 4096 * OUT_F * 4;      // 33554432

  if (ws_size >= PART_OFF + PART_BYTES) {
    float* wsp = (float*)d_ws;
    unsigned short* wp2 = (unsigned short*)((char*)d_ws + WP_OFF);
    float* part = (float*)((char*)d_ws + PART_OFF);
    kan_scale8<<<8, 256, 0, stream>>>(sca, wsp);
    kan_pack<<<256, 256, 0, stream>>>(sw, bw, wsp, wp2);
    kan_main<<<256, NTHREADS, 0, stream>>>(x, wp2, part, 0);
    kan_reduce<<<1024, 256, 0, stream>>>(part, out);
  } else if (ws_size >= PART_OFF) {
    float* wsp = (float*)d_ws;
    unsigned short* wp2 = (unsigned short*)((char*)d_ws + WP_OFF);
    hipMemsetAsync(d_out, 0, (size_t)out_size * sizeof(float), stream);
    kan_scale8<<<8, 256, 0, stream>>>(sca, wsp);
    kan_pack<<<256, 256, 0, stream>>>(sw, bw, wsp, wp2);
    kan_main<<<256, NTHREADS, 0, stream>>>(x, wp2, out, 1);
  } else {
    kan_naive<<<4096, 256, 0, stream>>>(x, bw, sw, sca, out);
  }
}